// Round 6
// baseline (546.397 us; speedup 1.0000x reference)
//
#include <hip/hip_runtime.h>

typedef unsigned short u16;
typedef short bf16x8 __attribute__((ext_vector_type(8)));
typedef float f32x4 __attribute__((ext_vector_type(4)));

__device__ inline u16 f2bf(float f) {
  unsigned u = __float_as_uint(f);
  u += 0x7fff + ((u >> 16) & 1);
  return (u16)(u >> 16);
}

__device__ inline void gl_lds16(const u16* g, u16* l) {
  __builtin_amdgcn_global_load_lds((const __attribute__((address_space(1))) void*)g,
                                   (__attribute__((address_space(3))) void*)l, 16, 0, 0);
}

// ---------------- fused prep: transposes + weight prep in ONE launch ----------------
// blocks [0,1024): anchor transpose; [1024,2048): positive transpose; [2048,2560): weights.
__global__ __launch_bounds__(256) void prep_all(const float* __restrict__ anchor,
                                                const float* __restrict__ positive,
                                                u16* __restrict__ A_t, u16* __restrict__ Pos_t,
                                                const float* __restrict__ Ww,
                                                const float* __restrict__ W2,
                                                const float* __restrict__ b2,
                                                const float* __restrict__ W1,
                                                u16* __restrict__ W2p, float* __restrict__ b2p,
                                                u16* __restrict__ W1b, u16* __restrict__ Wwb) {
  __shared__ u16 T[64 * 256];  // 32 KB, chunk-swizzled: chunk(p,cc) = p*32 + (cc ^ ((p>>2)&15))
  const int tid = threadIdx.x;

  if (blockIdx.x >= 2048) {  // ---- weight prep ----
    int g = (blockIdx.x - 2048) * 256 + tid;  // 131072 threads
    W1b[g] = f2bf(W1[g]);
    if (g < 65536) Wwb[g] = f2bf(Ww[g]);
    int d = g >> 9, h = g & 511;
    float s = 0.f;
    for (int c = 0; c < 256; c++) s += Ww[d * 256 + c] * W2[c * 512 + h];
    W2p[g] = f2bf(s);
    if (g < 256) {
      float t = 0.f;
      for (int c = 0; c < 256; c++) t += Ww[g * 256 + c] * b2[c];
      b2p[g] = t;
    }
    return;
  }

  // ---- transpose: [1024 b][256 c][64 p] fp32 -> [64 p][1024 b][256 c] bf16 ----
  const float* in = (blockIdx.x & 1024) ? positive : anchor;
  u16* outp = (blockIdx.x & 1024) ? Pos_t : A_t;
  const int b = blockIdx.x & 1023;
  const f32x4* in4 = (const f32x4*)in + (size_t)b * 4096;

  #pragma unroll
  for (int i = 0; i < 16; i++) {
    int local = i * 256 + tid;
    int c = local >> 4;            // 0..255
    int p4 = (local & 15) << 2;    // 0..60
    f32x4 v = __builtin_nontemporal_load(&in4[local]);
    int cc = c >> 3, co = c & 7;
    #pragma unroll
    for (int k = 0; k < 4; k++) {
      int p = p4 + k;
      int chunk = p * 32 + (cc ^ ((p >> 2) & 15));
      T[chunk * 8 + co] = f2bf(v[k]);
    }
  }
  __syncthreads();

  u16* ob = outp + (size_t)b * 256;
  #pragma unroll
  for (int j = 0; j < 8; j++) {
    int idx = j * 256 + tid;       // chunk id: 32 chunks per row
    int row = idx >> 5;            // p
    int col16 = idx & 31;          // cc
    int chunk = row * 32 + (col16 ^ ((row >> 2) & 15));
    bf16x8 vv = *(const bf16x8*)&T[chunk * 8];
    *(bf16x8*)&ob[((size_t)row << 18) + col16 * 8] = vv;
  }
}

// ---------------- bf16 GEMM (round-4 structure): C = epi(A@B^T + bias) ----------------
// 128x128 tile, BK=64, 256 threads (4 waves, 2x2 of 64x64), 16x16x32 MFMA.
// XCD-aware remap: i -> xcd = i&7; all n-blocks of an A-panel on one XCD.
__global__ __launch_bounds__(256, 3)
void gemm_bt(const u16* __restrict__ A1, const u16* __restrict__ B1, int K1len,
             const float* __restrict__ bias, u16* __restrict__ C, int N, int relu,
             int lognbx) {
  __shared__ u16 As[128 * 64];
  __shared__ u16 Bs[128 * 64];
  const int tid = threadIdx.x;
  const int lane = tid & 63;
  const int wave = tid >> 6;
  const int wm = wave & 1;
  const int wn = wave >> 1;
  const int i_d = blockIdx.y * gridDim.x + blockIdx.x;
  const int xcd = i_d & 7;
  const int slot = i_d >> 3;
  const int bx = slot & ((1 << lognbx) - 1);
  const int by = xcd * (gridDim.y >> 3) + (slot >> lognbx);
  const int m0 = by * 128;
  const int n0 = bx * 128;
  const int q = lane >> 4;
  const int l15 = lane & 15;

  f32x4 acc[4][4];
  #pragma unroll
  for (int i = 0; i < 4; i++)
    #pragma unroll
    for (int j = 0; j < 4; j++) acc[i][j] = (f32x4)(0.0f);

  const int nkt = K1len >> 6;
  for (int kt = 0; kt < nkt; kt++) {
    #pragma unroll
    for (int c = 0; c < 4; c++) {
      int chunk = c * 256 + tid;     // 0..1023 ; 8 chunks of 16B per row
      int row = chunk >> 3;
      int cg = (chunk & 7) ^ (row & 7);
      gl_lds16(A1 + (size_t)(m0 + row) * K1len + kt * 64 + cg * 8, &As[chunk * 8]);
      gl_lds16(B1 + (size_t)(n0 + row) * K1len + kt * 64 + cg * 8, &Bs[chunk * 8]);
    }
    __syncthreads();
    #pragma unroll
    for (int ks = 0; ks < 2; ks++) {
      bf16x8 af[4], bfr[4];
      #pragma unroll
      for (int i = 0; i < 4; i++) {
        int row = wm * 64 + i * 16 + l15;
        af[i] = *(const bf16x8*)&As[row * 64 + (((ks * 4 + q) ^ (row & 7)) * 8)];
      }
      #pragma unroll
      for (int j = 0; j < 4; j++) {
        int row = wn * 64 + j * 16 + l15;
        bfr[j] = *(const bf16x8*)&Bs[row * 64 + (((ks * 4 + q) ^ (row & 7)) * 8)];
      }
      #pragma unroll
      for (int i = 0; i < 4; i++)
        #pragma unroll
        for (int j = 0; j < 4; j++)
          acc[i][j] = __builtin_amdgcn_mfma_f32_16x16x32_bf16(af[i], bfr[j], acc[i][j], 0, 0, 0);
    }
    __syncthreads();
  }

  float bv[4];
  #pragma unroll
  for (int j = 0; j < 4; j++) bv[j] = bias[n0 + wn * 64 + j * 16 + l15];

  #pragma unroll
  for (int i = 0; i < 4; i++) {
    #pragma unroll
    for (int r = 0; r < 4; r++) {
      int row = m0 + wm * 64 + i * 16 + q * 4 + r;
      u16* crow = C + (size_t)row * N + n0 + wn * 64 + l15;
      #pragma unroll
      for (int j = 0; j < 4; j++) {
        float v = acc[i][j][r] + bv[j];
        if (relu) v = fmaxf(v, 0.0f);
        crow[j * 16] = f2bf(v);
      }
    }
  }
}

// ---------------- fused pred + logits + rowmax ----------------
// Per block (1024 blocks, 512 thr): 64 rows of one p.
// Phase 1: pred[64][256] = A@Ww^T + hidden@W2p^T + b2p, accumulated in regs.
//   A tile + hidden (two 256-col halves) staged via gl_lds16 in two 32KB ping-pong
//   buffers (H1 overwrites the A buffer after A's last use). Weights read direct
//   from L2-hot global, col-partitioned across waves (zero redundancy).
// Phase 2: pred (bf16 in LDS) @ post[p]^T + rowmax + NT store  == old logits_k.
// Remap: p = (L&7)+8*(L>>7) -> all 16 blocks of a p on one XCD.
__global__ __launch_bounds__(512, 2)
void pred_logits(const u16* __restrict__ A, const u16* __restrict__ hidden,
                 const u16* __restrict__ Wwb, const u16* __restrict__ W2pb,
                 const float* __restrict__ b2p, const u16* __restrict__ post,
                 float* __restrict__ out) {
  __shared__ u16 bufA[64 * 256];   // 32 KB: A tile, then H1
  __shared__ u16 bufB[64 * 256];   // 32 KB: H0, then pred (bf16)
  __shared__ float pmax[8][64];
  const int tid = threadIdx.x;
  const int lane = tid & 63;
  const int wave = tid >> 6;
  const int q = lane >> 4;
  const int l15 = lane & 15;
  const int L = blockIdx.x;
  const int p = (L & 7) + ((L >> 7) << 3);
  const int m0 = ((L >> 3) & 15) * 64;          // row base within p
  const size_t m0g = (size_t)p * 1024 + m0;     // global row base
  const u16* Ap = A + (m0g << 8);
  const u16* Hp = hidden + (m0g << 9);
  const u16* Bp = post + ((size_t)p << 18);

  // stage A -> bufA, H0 -> bufB (2048 16B-chunks each; swizzle chunk^(row&7))
  #pragma unroll
  for (int c = 0; c < 4; c++) {
    int chunk = c * 512 + tid;
    int row = chunk >> 5;
    int cg = (chunk & 31) ^ (row & 7);
    gl_lds16(Ap + row * 256 + cg * 8, &bufA[chunk * 8]);
    gl_lds16(Hp + (size_t)row * 512 + cg * 8, &bufB[chunk * 8]);
  }

  f32x4 accp[4][2];
  #pragma unroll
  for (int i = 0; i < 4; i++)
    #pragma unroll
    for (int j = 0; j < 2; j++) accp[i][j] = (f32x4)(0.0f);

  const int nb = wave * 32;   // this wave's 32 pred-cols

  __syncthreads();

#define PSTEP(SRC, BG, BS, BOFF, KT)                                                     \
  {                                                                                      \
    bf16x8 bfr[2], afr[4];                                                               \
    _Pragma("unroll")                                                                    \
    for (int j = 0; j < 2; j++)                                                          \
      bfr[j] = *(const bf16x8*)&(BG)[(size_t)(nb + j * 16 + l15) * (BS) + (BOFF) + (KT) * 32 + q * 8]; \
    _Pragma("unroll")                                                                    \
    for (int i = 0; i < 4; i++) {                                                        \
      int row = i * 16 + l15;                                                            \
      afr[i] = *(const bf16x8*)&(SRC)[row * 256 + ((((KT) * 4 + q) ^ (row & 7)) * 8)];   \
    }                                                                                    \
    _Pragma("unroll")                                                                    \
    for (int i = 0; i < 4; i++)                                                          \
      _Pragma("unroll")                                                                  \
      for (int j = 0; j < 2; j++)                                                        \
        accp[i][j] = __builtin_amdgcn_mfma_f32_16x16x32_bf16(afr[i], bfr[j], accp[i][j], 0, 0, 0); \
  }

  // K-seg 1: A @ Ww^T  (A in bufA)
  #pragma unroll
  for (int kt = 0; kt < 8; kt++) PSTEP(bufA, Wwb, 256, 0, kt)
  // K-seg 2: H0 @ W2p[:,0:256]^T  (H0 in bufB)
  #pragma unroll
  for (int kt = 0; kt < 8; kt++) PSTEP(bufB, W2pb, 512, 0, kt)

  __syncthreads();  // all waves done with bufA (A) and bufB (H0)

  // restage H1 -> bufA
  #pragma unroll
  for (int c = 0; c < 4; c++) {
    int chunk = c * 512 + tid;
    int row = chunk >> 5;
    int cg = (chunk & 31) ^ (row & 7);
    gl_lds16(Hp + (size_t)row * 512 + 256 + cg * 8, &bufA[chunk * 8]);
  }
  __syncthreads();

  // K-seg 3: H1 @ W2p[:,256:512]^T
  #pragma unroll
  for (int kt = 0; kt < 8; kt++) PSTEP(bufA, W2pb, 512, 256, kt)
#undef PSTEP

  // pred (+b2p) -> bufB as bf16, swizzled like an A-tile
  {
    float bv[2];
    #pragma unroll
    for (int j = 0; j < 2; j++) bv[j] = b2p[nb + j * 16 + l15];
    #pragma unroll
    for (int i = 0; i < 4; i++)
      #pragma unroll
      for (int r = 0; r < 4; r++) {
        int row = i * 16 + q * 4 + r;
        #pragma unroll
        for (int j = 0; j < 2; j++) {
          int col = nb + j * 16 + l15;
          bufB[row * 256 + (((col >> 3) ^ (row & 7)) << 3) + (col & 7)] =
              f2bf(accp[i][j][r] + bv[j]);
        }
      }
  }
  __syncthreads();  // pred visible

  // ---- phase 2: logits = pred @ post^T, rowmax, NT store ----
  f32x4 acc[4][8];
  #pragma unroll
  for (int i = 0; i < 4; i++)
    #pragma unroll
    for (int j = 0; j < 8; j++) acc[i][j] = (f32x4)(0.0f);

  const int nbase = wave * 128;
  #pragma unroll
  for (int kt = 0; kt < 8; kt++) {
    bf16x8 bfr[8];
    #pragma unroll
    for (int j = 0; j < 8; j++) {
      int n = nbase + j * 16 + l15;
      bfr[j] = *(const bf16x8*)&Bp[(size_t)n * 256 + kt * 32 + q * 8];
    }
    bf16x8 afr[4];
    #pragma unroll
    for (int i = 0; i < 4; i++) {
      int row = i * 16 + l15;
      afr[i] = *(const bf16x8*)&bufB[row * 256 + ((((kt << 2) + q) ^ (row & 7)) * 8)];
    }
    #pragma unroll
    for (int i = 0; i < 4; i++)
      #pragma unroll
      for (int j = 0; j < 8; j++)
        acc[i][j] = __builtin_amdgcn_mfma_f32_16x16x32_bf16(afr[i], bfr[j], acc[i][j], 0, 0, 0);
  }

  float rm[4][4];
  #pragma unroll
  for (int i = 0; i < 4; i++)
    #pragma unroll
    for (int r = 0; r < 4; r++) {
      float m = acc[i][0][r];
      #pragma unroll
      for (int j = 1; j < 8; j++) m = fmaxf(m, acc[i][j][r]);
      m = fmaxf(m, __shfl_xor(m, 1, 64));
      m = fmaxf(m, __shfl_xor(m, 2, 64));
      m = fmaxf(m, __shfl_xor(m, 4, 64));
      m = fmaxf(m, __shfl_xor(m, 8, 64));
      rm[i][r] = m;
    }
  if (l15 == 0) {
    #pragma unroll
    for (int i = 0; i < 4; i++)
      #pragma unroll
      for (int r = 0; r < 4; r++) pmax[wave][i * 16 + q * 4 + r] = rm[i][r];
  }
  __syncthreads();
  #pragma unroll
  for (int i = 0; i < 4; i++)
    #pragma unroll
    for (int r = 0; r < 4; r++) {
      int row = i * 16 + q * 4 + r;
      float m = pmax[0][row];
      #pragma unroll
      for (int w = 1; w < 8; w++) m = fmaxf(m, pmax[w][row]);
      rm[i][r] = m;
    }

  float* ob = out + ((size_t)p << 20) + (size_t)m0 * 1024 + nbase + l15;
  #pragma unroll
  for (int i = 0; i < 4; i++)
    #pragma unroll
    for (int r = 0; r < 4; r++) {
      float* orow = ob + (size_t)(i * 16 + q * 4 + r) * 1024;
      #pragma unroll
      for (int j = 0; j < 8; j++)
        __builtin_nontemporal_store(acc[i][j][r] - rm[i][r], &orow[j * 16]);
    }
}

// ---------------- launch ----------------

extern "C" void kernel_launch(void* const* d_in, const int* in_sizes, int n_in,
                              void* d_out, int out_size, void* d_ws, size_t ws_size,
                              hipStream_t stream) {
  const float* anchor   = (const float*)d_in[0];
  const float* positive = (const float*)d_in[1];
  const float* W1       = (const float*)d_in[2];
  const float* b1       = (const float*)d_in[3];
  const float* W2       = (const float*)d_in[4];
  const float* b2       = (const float*)d_in[5];
  const float* Ww       = (const float*)d_in[6];
  float* out = (float*)d_out;
  char* ws = (char*)d_ws;

  u16*   A_t    = (u16*)(ws + 0x00000000);  // 32 MB  [64][1024][256] bf16
  u16*   Pos_t  = (u16*)(ws + 0x02000000);  // 32 MB
  u16*   hidden = (u16*)(ws + 0x04000000);  // 64 MB  [65536][512] bf16
  u16*   W1b    = (u16*)(ws + 0x0A000000);  // 256 KB
  u16*   Wwb    = (u16*)(ws + 0x0A100000);  // 128 KB
  u16*   W2pb   = (u16*)(ws + 0x0A200000);  // 512 KB
  float* b2p    = (float*)(ws + 0x0A300000);

  // transposes + weight prep in one launch
  prep_all<<<2560, 256, 0, stream>>>(anchor, positive, A_t, Pos_t,
                                     Ww, W2, b2, W1, W2pb, b2p, W1b, Wwb);

  // hidden = relu(A_t @ W1^T + b1): M=65536, N=512, K=256
  gemm_bt<<<dim3(4, 512), 256, 0, stream>>>(A_t, W1b, 256, b1, hidden, 512, 1, 2);

  // pred (in-LDS) + logits + rowmax, fused; pred never hits memory
  pred_logits<<<1024, 512, 0, stream>>>(A_t, hidden, Wwb, W2pb, b2p, Pos_t, out);
}